// Round 18
// baseline (105.386 us; speedup 1.0000x reference)
//
#include <hip/hip_runtime.h>
#include <hip/hip_bf16.h>

#define LN_EPS 1e-5f
#define BSH   7                  // bucket shift: 128 nodes/bucket
#define BNODE 128
#define EPB   8192               // edges per bucket block
#define CAP   4096               // max edges per bucket stageable in LDS

typedef __attribute__((ext_vector_type(8))) short bf16x8;
typedef __attribute__((ext_vector_type(4))) float floatx4;

#define F2BF(f) ((unsigned short)((__float_as_uint(f) + 0x7FFF + \
                ((__float_as_uint(f) >> 16) & 1)) >> 16))

// ------- cvt (x->bf16) + bucket histogram fused (hist rides under cvt) -------
// All blocks convert their x slice; blocks < ebl additionally histogram their
// 8192-edge chunk in LDS and flush one atomic per bucket. Independent work ->
// the ~8us hist cost hides under cvt's memory time.
__global__ __launch_bounds__(256) void cvt_hist_kernel(
    const float* __restrict__ x, unsigned short* __restrict__ xb, int n64,
    const int* __restrict__ ei, int* __restrict__ bcount, int E, int NB, int ebl)
{
    __shared__ int lhist[1024];
    int t = threadIdx.x;

    if ((int)blockIdx.x < ebl) {
        for (int b = t; b < NB; b += 256) lhist[b] = 0;
        __syncthreads();
        int base = blockIdx.x * EPB;
        #pragma unroll 4
        for (int i = 0; i < EPB / 256; ++i) {
            int e = base + i * 256 + t;
            if (e < E) atomicAdd(&lhist[ei[E + e] >> BSH], 1);
        }
        __syncthreads();
        for (int b = t; b < NB; b += 256) {
            int c = lhist[b];
            if (c) atomicAdd(&bcount[b], c);
        }
    }

    int i = (blockIdx.x * 256 + t) * 8;
    if (i < n64) {
        float4 a = *(const float4*)&x[i];
        float4 b = *(const float4*)&x[i + 4];
        uint4 o;
        o.x = (unsigned)F2BF(a.x) | ((unsigned)F2BF(a.y) << 16);
        o.y = (unsigned)F2BF(a.z) | ((unsigned)F2BF(a.w) << 16);
        o.z = (unsigned)F2BF(b.x) | ((unsigned)F2BF(b.y) << 16);
        o.w = (unsigned)F2BF(b.z) | ((unsigned)F2BF(b.w) << 16);
        *(uint4*)&xb[i] = o;
    }
}

// ---------------- bucket scan: 1 block, exclusive scan of <=1024 buckets ----------------
__global__ __launch_bounds__(256) void bucket_scan_kernel(
    const int* __restrict__ bcount, int* __restrict__ bbase,
    int* __restrict__ gcursor, int NB, int E)
{
    __shared__ int wsum[4];
    int t = threadIdx.x;
    int v[4]; int tsum = 0;
    #pragma unroll
    for (int i = 0; i < 4; ++i) {
        int idx = t * 4 + i;
        v[i] = (idx < NB) ? bcount[idx] : 0;
        tsum += v[i];
    }
    int lane = t & 63, w = t >> 6;
    int sc = tsum;
    #pragma unroll
    for (int off = 1; off < 64; off <<= 1) {
        int y = __shfl_up(sc, off);
        if (lane >= off) sc += y;
    }
    if (lane == 63) wsum[w] = sc;
    __syncthreads();
    int woff = 0;
    for (int j = 0; j < w; ++j) woff += wsum[j];
    int run = woff + sc - tsum;
    #pragma unroll
    for (int i = 0; i < 4; ++i) {
        int idx = t * 4 + i;
        if (idx < NB) { bbase[idx] = run; gcursor[idx] = run; }
        run += v[i];
    }
    if (t == 255) bbase[NB] = E;
}

// ---------------- bucket scatter (round-10 proven) ----------------
__global__ __launch_bounds__(256) void bucket_scatter_kernel(
    const int* __restrict__ ei,
    int* __restrict__ gcursor,
    int* __restrict__ ebuf,
    int E, int NB)
{
    __shared__ int lhist[1024];
    __shared__ int lbase[1024];
    __shared__ int lcur[1024];

    int t = threadIdx.x;
    int base = blockIdx.x * EPB;

    for (int b = t; b < NB; b += 256) lhist[b] = 0;
    __syncthreads();

    #pragma unroll 4
    for (int i = 0; i < EPB / 256; ++i) {
        int e = base + i * 256 + t;          // coalesced
        if (e < E) atomicAdd(&lhist[ei[E + e] >> BSH], 1);
    }
    __syncthreads();

    for (int b = t; b < NB; b += 256) {
        int c = lhist[b];
        lbase[b] = c ? atomicAdd(&gcursor[b], c) : 0;
        lcur[b]  = 0;
    }
    __syncthreads();

    #pragma unroll 4
    for (int i = 0; i < EPB / 256; ++i) {
        int e = base + i * 256 + t;
        if (e < E) {
            int src = ei[e];
            int dst = ei[E + e];
            int b   = dst >> BSH;
            int pos = lbase[b] + atomicAdd(&lcur[b], 1);
            ebuf[pos] = src | ((dst & (BNODE - 1)) << 17);
        }
    }
}

// ---------------- csrsort v2 (round-17 proven) ----------------
__global__ __launch_bounds__(256) void csrsort_kernel(
    const int* __restrict__ bbase,
    const int* __restrict__ ebuf,
    int* __restrict__ esrc,
    int* __restrict__ rowstart,
    int N)
{
    __shared__ int lcnt[BNODE];
    __shared__ int lpre[BNODE + 1];
    __shared__ int lcur[BNODE];
    __shared__ int sorted[CAP];

    int t    = threadIdx.x;
    int b    = blockIdx.x;
    int nb0  = b << BSH;
    int nloc = min(BNODE, N - nb0);
    int s0   = bbase[b];
    int s1   = bbase[b + 1];
    int cnt  = s1 - s0;

    if (t < BNODE) { lcnt[t] = 0; lcur[t] = 0; }
    __syncthreads();

    for (int i = s0 + t; i < s1; i += 256)
        atomicAdd(&lcnt[(unsigned)ebuf[i] >> 17], 1);
    __syncthreads();

    if (t < 64) {   // wave 0: scan 128 counts, 2 per lane
        int v0 = lcnt[2 * t], v1 = lcnt[2 * t + 1];
        int p = v0 + v1, sc = p;
        #pragma unroll
        for (int off = 1; off < 64; off <<= 1) {
            int y = __shfl_up(sc, off);
            if (t >= off) sc += y;
        }
        int excl = sc - p;
        lpre[2 * t]     = excl;
        lpre[2 * t + 1] = excl + v0;
        if (t == 63) lpre[BNODE] = excl + p;   // == cnt
    }
    __syncthreads();

    if (t <= nloc) rowstart[nb0 + t] = s0 + lpre[t];

    if (cnt <= CAP) {
        for (int i = s0 + t; i < s1; i += 256) {
            int p = ebuf[i];
            int n = (unsigned)p >> 17;
            int slot = lpre[n] + atomicAdd(&lcur[n], 1);
            sorted[slot] = p & 0x1FFFF;
        }
        __syncthreads();
        for (int i = t; i < cnt; i += 256) esrc[s0 + i] = sorted[i];  // coalesced
    } else {
        for (int i = s0 + t; i < s1; i += 256) {
            int p = ebuf[i];
            int n = (unsigned)p >> 17;
            int slot = s0 + lpre[n] + atomicAdd(&lcur[n], 1);
            esrc[slot] = p & 0x1FFFF;
        }
    }
}

// ---------------- gather: bf16 rows in, bf16 mean out ----------------
// One node per wave; 4 edge-groups x 16 lanes x 8B (uint2 = 4 bf16) per row
// load. Mean now written in bf16 (halves the mean round-trip; mfma stages it
// verbatim). No aliasing with out anymore (meanb lives in ws).
__global__ __launch_bounds__(256) void gather_kernel(
    const unsigned short* __restrict__ xb,
    const int*   __restrict__ rowstart,
    const int*   __restrict__ esrc,
    unsigned short* __restrict__ meanb,
    int N)
{
    int tid  = threadIdx.x;
    int lane = tid & 63;
    int g    = lane >> 4;
    int sub  = lane & 15;
    int node = blockIdx.x * 4 + (tid >> 6);
    if (node >= N) return;
    int s0 = rowstart[node], s1 = rowstart[node + 1];

    float a0 = 0.f, a1 = 0.f, a2 = 0.f, a3 = 0.f;
    float b0 = 0.f, b1 = 0.f, b2 = 0.f, b3 = 0.f;
    int e = s0 + g;
    for (; e + 4 < s1; e += 8) {
        int sA = esrc[e];
        int sB = esrc[e + 4];
        uint2 va = *(const uint2*)&xb[(size_t)sA * 64 + sub * 4];
        uint2 vb = *(const uint2*)&xb[(size_t)sB * 64 + sub * 4];
        a0 += __uint_as_float(va.x << 16);
        a1 += __uint_as_float(va.x & 0xFFFF0000u);
        a2 += __uint_as_float(va.y << 16);
        a3 += __uint_as_float(va.y & 0xFFFF0000u);
        b0 += __uint_as_float(vb.x << 16);
        b1 += __uint_as_float(vb.x & 0xFFFF0000u);
        b2 += __uint_as_float(vb.y << 16);
        b3 += __uint_as_float(vb.y & 0xFFFF0000u);
    }
    if (e < s1) {
        uint2 va = *(const uint2*)&xb[(size_t)esrc[e] * 64 + sub * 4];
        a0 += __uint_as_float(va.x << 16);
        a1 += __uint_as_float(va.x & 0xFFFF0000u);
        a2 += __uint_as_float(va.y << 16);
        a3 += __uint_as_float(va.y & 0xFFFF0000u);
    }
    a0 += b0; a1 += b1; a2 += b2; a3 += b3;

    a0 += __shfl_xor(a0, 32); a1 += __shfl_xor(a1, 32);
    a2 += __shfl_xor(a2, 32); a3 += __shfl_xor(a3, 32);
    a0 += __shfl_xor(a0, 16); a1 += __shfl_xor(a1, 16);
    a2 += __shfl_xor(a2, 16); a3 += __shfl_xor(a3, 16);

    if (g == 0) {
        float inv = 1.0f / fmaxf((float)(s1 - s0), 1.0f);
        float m0 = a0 * inv, m1 = a1 * inv, m2 = a2 * inv, m3 = a3 * inv;
        uint2 o;
        o.x = (unsigned)F2BF(m0) | ((unsigned)F2BF(m1) << 16);
        o.y = (unsigned)F2BF(m2) | ((unsigned)F2BF(m3) << 16);
        *(uint2*)&meanb[(size_t)node * 64 + sub * 4] = o;   // 16 lanes x 8B
    }
}

// ---------------- MFMA MLP + LayerNorm + ELU ----------------
// A = [meanb|xb] staged verbatim (both bf16 already); B = [Wl^T;Wr^T] cvt'd.
// LDS stride 136 (16B-aligned b128 reads; 2 lanes/bank = free). C/D layout:
// col=lane&15, row=(lane>>4)*4+reg (m89-verified). LN in-wave (16-lane shfl).
__global__ __launch_bounds__(256) void mfma_mlp_kernel(
    const unsigned short* __restrict__ xb,
    const unsigned short* __restrict__ meanb,
    const float* __restrict__ Wl,
    const float* __restrict__ Wr,
    const float* __restrict__ bias,
    const float* __restrict__ gamma,
    const float* __restrict__ beta,
    float* __restrict__ out,
    int N)
{
    __shared__ short smA[64][136];   // [node][k]  k<64: mean, k>=64: x
    __shared__ short smB[64][136];   // [j][k]     k<64: Wl[j], k>=64: Wr[j]

    int tid  = threadIdx.x;
    int lane = tid & 63;
    int w    = tid >> 6;
    int lo   = lane & 15;
    int hi   = lane >> 4;
    int nbase = blockIdx.x * 64;

    // weights f32 -> bf16
    #pragma unroll
    for (int it = 0; it < 4; ++it) {
        int slot = tid + it * 256;          // 0..1023 float4 slots
        int row  = slot >> 4;
        int c4   = (slot & 15) * 4;
        float4 wl = *(const float4*)&Wl[slot * 4];
        float4 wr = *(const float4*)&Wr[slot * 4];
        uint2 lp, rp;
        lp.x = (unsigned)F2BF(wl.x) | ((unsigned)F2BF(wl.y) << 16);
        lp.y = (unsigned)F2BF(wl.z) | ((unsigned)F2BF(wl.w) << 16);
        rp.x = (unsigned)F2BF(wr.x) | ((unsigned)F2BF(wr.y) << 16);
        rp.y = (unsigned)F2BF(wr.z) | ((unsigned)F2BF(wr.w) << 16);
        *(uint2*)&smB[row][c4]      = lp;   // row=j
        *(uint2*)&smB[row][64 + c4] = rp;
    }
    // A halves: copy bf16 rows verbatim (16B chunks, coalesced)
    #pragma unroll
    for (int it = 0; it < 2; ++it) {
        int s   = tid + it * 256;           // 0..511 slots of 8 bf16
        int row = s >> 3;
        int o8  = (s & 7) * 8;
        size_t roff = (size_t)(nbase + row < N ? nbase + row : 0) * 64 + o8;
        uint4 vm = *(const uint4*)&meanb[roff];
        uint4 vx = *(const uint4*)&xb[roff];
        *(uint4*)&smA[row][o8]      = vm;
        *(uint4*)&smA[row][64 + o8] = vx;
    }
    __syncthreads();

    bf16x8 a0 = *(const bf16x8*)&smA[w * 16 + lo][ 0 + hi * 8];
    bf16x8 a1 = *(const bf16x8*)&smA[w * 16 + lo][32 + hi * 8];
    bf16x8 a2 = *(const bf16x8*)&smA[w * 16 + lo][64 + hi * 8];
    bf16x8 a3 = *(const bf16x8*)&smA[w * 16 + lo][96 + hi * 8];

    floatx4 c[4];
    #pragma unroll
    for (int ct = 0; ct < 4; ++ct) {
        float b = bias[ct * 16 + lo];
        c[ct] = (floatx4){b, b, b, b};
    }

    #pragma unroll
    for (int ct = 0; ct < 4; ++ct) {
        int j = ct * 16 + lo;
        bf16x8 b0 = *(const bf16x8*)&smB[j][ 0 + hi * 8];
        bf16x8 b1 = *(const bf16x8*)&smB[j][32 + hi * 8];
        bf16x8 b2 = *(const bf16x8*)&smB[j][64 + hi * 8];
        bf16x8 b3 = *(const bf16x8*)&smB[j][96 + hi * 8];
        c[ct] = __builtin_amdgcn_mfma_f32_16x16x32_bf16(a0, b0, c[ct], 0, 0, 0);
        c[ct] = __builtin_amdgcn_mfma_f32_16x16x32_bf16(a1, b1, c[ct], 0, 0, 0);
        c[ct] = __builtin_amdgcn_mfma_f32_16x16x32_bf16(a2, b2, c[ct], 0, 0, 0);
        c[ct] = __builtin_amdgcn_mfma_f32_16x16x32_bf16(a3, b3, c[ct], 0, 0, 0);
    }

    float s[4], q[4];
    #pragma unroll
    for (int p = 0; p < 4; ++p) {
        s[p] = c[0][p] + c[1][p] + c[2][p] + c[3][p];
        q[p] = c[0][p]*c[0][p] + c[1][p]*c[1][p]
             + c[2][p]*c[2][p] + c[3][p]*c[3][p];
        #pragma unroll
        for (int off = 1; off < 16; off <<= 1) {
            s[p] += __shfl_xor(s[p], off);
            q[p] += __shfl_xor(q[p], off);
        }
    }

    #pragma unroll
    for (int p = 0; p < 4; ++p) {
        int node = nbase + w * 16 + hi * 4 + p;   // C row = hi*4+p
        if (node >= N) continue;
        float mu  = s[p] * (1.0f / 64.0f);
        float var = q[p] * (1.0f / 64.0f) - mu * mu;
        float rr  = rsqrtf(var + LN_EPS);
        #pragma unroll
        for (int ct = 0; ct < 4; ++ct) {
            int col = ct * 16 + lo;
            float hn = (c[ct][p] - mu) * rr * gamma[col] + beta[col];
            hn = hn > 0.f ? hn : __expf(hn) - 1.0f;
            out[(size_t)node * 64 + col] = hn;
        }
    }
}

extern "C" void kernel_launch(void* const* d_in, const int* in_sizes, int n_in,
                              void* d_out, int out_size, void* d_ws, size_t ws_size,
                              hipStream_t stream) {
    const float* x     = (const float*)d_in[0];
    const int*   ei    = (const int*)  d_in[1];
    const float* Wl    = (const float*)d_in[2];
    const float* Wr    = (const float*)d_in[3];
    const float* bias  = (const float*)d_in[4];
    const float* gamma = (const float*)d_in[5];
    const float* beta  = (const float*)d_in[6];

    int N  = in_sizes[0] / 64;
    int E  = in_sizes[1] / 2;
    int NB = (N + BNODE - 1) >> BSH;       // 782 buckets

    unsigned short* xb    = (unsigned short*)d_ws;         // N*64 bf16
    unsigned short* meanb = xb + (size_t)N * 64;           // N*64 bf16
    int* bcount   = (int*)(meanb + (size_t)N * 64);        // NB
    int* bbase    = bcount + NB;            // NB+1
    int* gcursor  = bbase + (NB + 1);       // NB
    int* rowstart = gcursor + NB;           // N+1
    int* ebuf     = rowstart + (N + 1);     // E (packed src | dstlocal<<17)
    int* esrc     = ebuf + E;               // E (CSR-ordered src)

    hipMemsetAsync(bcount, 0, (size_t)NB * sizeof(int), stream);

    int ebl = (E + EPB - 1) / EPB;
    int cvtbl = (N * 64 + 2047) / 2048;
    cvt_hist_kernel<<<cvtbl, 256, 0, stream>>>(x, xb, N * 64, ei, bcount,
                                               E, NB, ebl);

    bucket_scan_kernel<<<1, 256, 0, stream>>>(bcount, bbase, gcursor, NB, E);

    bucket_scatter_kernel<<<ebl, 256, 0, stream>>>(ei, gcursor, ebuf, E, NB);

    csrsort_kernel<<<NB, 256, 0, stream>>>(bbase, ebuf, esrc, rowstart, N);

    gather_kernel<<<(N + 3) / 4, 256, 0, stream>>>(xb, rowstart, esrc, meanb, N);

    mfma_mlp_kernel<<<(N + 63) / 64, 256, 0, stream>>>(xb, meanb, Wl, Wr, bias,
                                                       gamma, beta,
                                                       (float*)d_out, N);
}